// Round 13
// baseline (332.444 us; speedup 1.0000x reference)
//
#include <hip/hip_runtime.h>

typedef __bf16 bf16x8 __attribute__((ext_vector_type(8)));
typedef float f32x4 __attribute__((ext_vector_type(4)));

#define WT_SLOT 65536              // elements per 256x256 bf16 weight slot (packed fragment order)
#define WS_GKEYS 0                 // 512 u32 (tb keys, br keys)
#define WS_VEC0  4096              // 256 f32
#define WS_COUNTS 8192             // 256 u32
#define WS_BASES 12288             // 256 u32
#define WS_IDX   16384             // 4096 i32
#define WS_WT    32768             // 12 slots * 131072 B (slot 11 = 3 packed-W0 minis)

#define TANH_K 2.8853900817779268f   // 2*log2(e); tanh layers have W,b pre-scaled by this
#define NPTS 262144

__device__ __forceinline__ unsigned fkey(float f) {
  unsigned u = __float_as_uint(f);
  return (u & 0x80000000u) ? ~u : (u | 0x80000000u);
}
__device__ __forceinline__ float unfkey(unsigned k) {
  unsigned u = (k & 0x80000000u) ? (k & 0x7FFFFFFFu) : ~k;
  return __uint_as_float(u);
}
// swizzled LDS byte offset for act tiles, row stride 512B.
// (r&15) spread: the 16 rows co-read by a 16-lane quarter hit 16 distinct 16B slots.
__device__ __forceinline__ int lds_off(int r, int cb) {
  return r * 512 + (cb ^ ((r & 15) << 4));
}
// tanh from pre-scaled input t = 2log2e*x : 1 - 2/(exp2(t)+1)
__device__ __forceinline__ float tanh_scaled(float t) {
  float e = __builtin_amdgcn_exp2f(t);
  return fmaf(__builtin_amdgcn_rcpf(e + 1.0f), -2.0f, 1.0f);
}
// T12-verified packed bf16 convert (2 f32 -> 1 u32)
__device__ __forceinline__ unsigned cvt_pk_bf16(float lo, float hi) {
  unsigned d;
  asm("v_cvt_pk_bf16_f32 %0, %1, %2" : "=v"(d) : "v"(lo), "v"(hi));
  return d;
}

// Packed B layout: element (n = nt*16 + (l&15), k = ks*32 + (l>>4)*8 + j) at
// linear ks*8192 + nt*512 + l*8 + j. Wave w (of 4) owns nt = 4w..4w+3 (cols 64w..64w+63).
__device__ __forceinline__ void load_bpair(const __bf16* wt, int wave, int lane, int p,
                                           bf16x8 b[8]) {
  const __bf16* base = wt + p * 16384 + wave * 2048 + lane * 8;
#pragma unroll
  for (int h = 0; h < 2; ++h)
#pragma unroll
    for (int i = 0; i < 4; ++i)
      b[h * 4 + i] = *(const bf16x8*)(base + h * 8192 + i * 512);
}

// Swapped-operand MFMA: mfma(W_frag, A_frag, acc) -> lane holds rows rt*16+(lane&15),
// cols cbase + (lane>>4)*4 + rg (4 consecutive). NRT = row-tiles in the act tile.
template <int NRT>
__device__ __forceinline__ void compute_pair(char* lds, const bf16x8 bc[8], int ksbase,
                                             int rlo, int khi2, f32x4 acc[NRT][4]) {
  __builtin_amdgcn_s_setprio(1);
#pragma unroll
  for (int h = 0; h < 2; ++h) {
    int cb = (ksbase + h) * 64 + khi2;   // byte column of this k-chunk
#pragma unroll
    for (int rt = 0; rt < NRT; ++rt) {
      bf16x8 av = *(const bf16x8*)(lds + lds_off(rt * 16 + rlo, cb));
#pragma unroll
      for (int i = 0; i < 4; ++i)
        acc[rt][i] = __builtin_amdgcn_mfma_f32_16x16x32_bf16(bc[h * 4 + i], av, acc[rt][i], 0, 0, 0);
    }
  }
  __builtin_amdgcn_s_setprio(0);
}

// bias is already inside acc (C-operand init); epilogue = activation + pack + store.
template <int NRT, bool TANH, bool WRITE, bool CMAX>
__device__ __forceinline__ void epilogue(char* lds, int lane, int wave,
                                         f32x4 acc[NRT][4], float* mbuf) {
  const int rlo = lane & 15;
  const int q4 = (lane >> 4) << 2;
#pragma unroll
  for (int i = 0; i < 4; ++i) {
    const int cbase = (wave * 4 + i) * 16 + q4;       // 4 consecutive cols per lane
    f32x4 cm;
#pragma unroll
    for (int rt = 0; rt < NRT; ++rt) {
      f32x4 v;
#pragma unroll
      for (int rg = 0; rg < 4; ++rg) {
        float t = acc[rt][i][rg];
        if (TANH) t = tanh_scaled(t);
        v[rg] = t;
      }
      if (WRITE) {
        uint2 pv;
        pv.x = cvt_pk_bf16(v[0], v[1]);
        pv.y = cvt_pk_bf16(v[2], v[3]);
        *(uint2*)(lds + lds_off(rt * 16 + rlo, 2 * cbase)) = pv;
      }
      if (CMAX) {
        if (rt == 0) cm = v;
        else {
#pragma unroll
          for (int rg = 0; rg < 4; ++rg) cm[rg] = fmaxf(cm[rg], v[rg]);
        }
      }
    }
    if (CMAX) {  // reduce over rows (lane&15 across lanes), cols distinct per (q,rg)
#pragma unroll
      for (int rg = 0; rg < 4; ++rg) {
#pragma unroll
        for (int off = 1; off <= 8; off <<= 1)
          cm[rg] = fmaxf(cm[rg], __shfl_xor(cm[rg], off, 64));
      }
      if (rlo == 0) *(f32x4*)(mbuf + cbase) = cm;
    }
  }
}

// acc init = bias (x TANH_K for tanh layers, whose W is pre-scaled likewise)
template <int NRT, bool TANH>
__device__ __forceinline__ void acc_init(f32x4 acc[NRT][4], const float* bias, int lane, int wave) {
  const int q4 = (lane >> 4) << 2;
#pragma unroll
  for (int i = 0; i < 4; ++i) {
    f32x4 bv = *(const f32x4*)(bias + (wave * 4 + i) * 16 + q4);
    if (TANH) {
#pragma unroll
      for (int rg = 0; rg < 4; ++rg) bv[rg] *= TANH_K;
    }
#pragma unroll
    for (int rt = 0; rt < NRT; ++rt) acc[rt][i] = bv;
  }
}

// One 256->256 layer. Precondition: b0 holds THIS layer's pair0. Post: b0 holds wt_next pair0.
// CMAX-only layers (WRITE=false) skip the pre-epilogue barrier (no act-tile stores).
template <int NRT, bool TANH, bool WRITE, bool CMAX>
__device__ __forceinline__ void layer256(char* lds, const __bf16* wt, const __bf16* wt_next,
                                         const float* bias, int lane, int wave, float* mbuf,
                                         bf16x8 b0[8], bf16x8 b1[8]) {
  const int rlo = lane & 15;
  const int khi2 = (lane >> 4) << 4;   // byte offset of k-subrange
  f32x4 acc[NRT][4];
  acc_init<NRT, TANH>(acc, bias, lane, wave);

  load_bpair(wt, wave, lane, 1, b1);
  compute_pair<NRT>(lds, b0, 0, rlo, khi2, acc);
  load_bpair(wt, wave, lane, 2, b0);
  compute_pair<NRT>(lds, b1, 2, rlo, khi2, acc);
  load_bpair(wt, wave, lane, 3, b1);
  compute_pair<NRT>(lds, b0, 4, rlo, khi2, acc);
  load_bpair(wt_next, wave, lane, 0, b0);   // prefetch next layer's pair0
  compute_pair<NRT>(lds, b1, 6, rlo, khi2, acc);

  if (WRITE) __syncthreads();               // act-tile reads done before overwrite
  epilogue<NRT, TANH, WRITE, CMAX>(lds, lane, wave, acc, mbuf);
  __syncthreads();
}

// layer0 (K=32) via MFMA; A-fragments (av) built in registers by the caller:
// lane<16 holds {x0,x1,x2,0...} for row rt*16+(lane&15); lanes>=16 all-zero.
template <int NRT>
__device__ __forceinline__ void layer0_mfma(char* lds, const bf16x8* av, const bf16x8 b0f[4],
                                            const float* bias, int lane, int wave) {
  f32x4 acc[NRT][4];
  acc_init<NRT, true>(acc, bias, lane, wave);
  __builtin_amdgcn_s_setprio(1);
#pragma unroll
  for (int rt = 0; rt < NRT; ++rt) {
#pragma unroll
    for (int i = 0; i < 4; ++i)
      acc[rt][i] = __builtin_amdgcn_mfma_f32_16x16x32_bf16(b0f[i], av[rt], acc[rt][i], 0, 0, 0);
  }
  __builtin_amdgcn_s_setprio(0);
  epilogue<NRT, true, true, false>(lds, lane, wave, acc, nullptr);
  __syncthreads();
}

// ------------------ weight convert/transpose/pack to bf16 (tanh layers pre-scaled) ------------------
struct ConvArgs { const float* src[14]; };
__global__ void K_conv(ConvArgs a, __bf16* wt, unsigned* gkeys) {
  int job = blockIdx.x, t = threadIdx.x, y = blockIdx.y;
  if (job == 14) {
    if (y == 0) { gkeys[t] = 0u; gkeys[256 + t] = 0u; }
    return;
  }
  if (job >= 11) {  // W0 minis: (3,256) fp32 -> one K=32 fragment chunk, zero-padded, tanh-scaled
    if (y >= 2) return;
    const float* s = a.src[job];
    __bf16* d = wt + (size_t)11 * WT_SLOT + (job - 11) * 8192;
#pragma unroll
    for (int it = 0; it < 16; ++it) {
      int p = y * 4096 + it * 256 + t;
      int nt = (p >> 9) & 15, ln = (p >> 3) & 63, j = p & 7;
      int n = nt * 16 + (ln & 15);
      int k = ((ln >> 4) << 3) + j;
      d[p] = (k < 3) ? (__bf16)(TANH_K * s[k * 256 + n]) : (__bf16)0.f;
    }
    return;
  }
  // jobs 0..10: tanh layers (all except job%3==2 within 0..8) scaled by TANH_K
  const float scale = (job >= 9 || (job % 3) != 2) ? TANH_K : 1.0f;
  const float* s = a.src[job];
  __bf16* d = wt + (size_t)job * WT_SLOT;
#pragma unroll
  for (int it = 0; it < 16; ++it) {
    int p = y * 4096 + it * 256 + t;                 // packed linear index
    int ks = p >> 13, nt = (p >> 9) & 15, ln = (p >> 3) & 63, j = p & 7;
    int n = nt * 16 + (ln & 15);
    int k = ks * 32 + ((ln >> 4) << 3) + j;
    d[p] = (__bf16)(scale * s[(k << 8) | n]);        // src is [K][N] fp32 (first 256 rows)
  }
}

// ------------------ big fused MLP (tb & br) + column max: 96-row tiles, 3 blocks/CU ------------------
struct BigArgs {
  const float* x;
  const __bf16* wt;
  const float* b0[2]; const float* b1[2]; const float* b2[2]; const float* b3[2];
  unsigned* gkeys;
};
__global__ __launch_bounds__(256, 3) void K_big(BigArgs a) {
  __shared__ char lds[49152];          // 96-row act tile
  __shared__ float mbuf[256];
  int tid = threadIdx.x, lane = tid & 63, wave = tid >> 6;
  int mlp = blockIdx.y;
  int row0 = blockIdx.x * 96;
  const __bf16* wt = a.wt + (size_t)(mlp * 3) * WT_SLOT;
  const __bf16* w0f = a.wt + (size_t)11 * WT_SLOT + mlp * 8192;
  // layer0 A-fragments in registers; row index clamped to N-1 (duplicate rows
  // can't change a column max, and tail rows are never stored anywhere).
  const int rlo = lane & 15;
  bf16x8 av[6];
  {
#pragma unroll
    for (int rt = 0; rt < 6; ++rt) {
      bf16x8 v;
#pragma unroll
      for (int j = 0; j < 8; ++j) v[j] = (__bf16)0.f;
      if (lane < 16) {
        int row = min(row0 + rt * 16 + rlo, NPTS - 1);
        const float* p = a.x + (size_t)row * 3;
        v[0] = (__bf16)p[0]; v[1] = (__bf16)p[1]; v[2] = (__bf16)p[2];
      }
      av[rt] = v;
    }
  }
  bf16x8 b0f[4];
#pragma unroll
  for (int i = 0; i < 4; ++i) b0f[i] = *(const bf16x8*)(w0f + (wave * 4 + i) * 512 + lane * 8);
  bf16x8 br0[8], br1[8];
  load_bpair(wt, wave, lane, 0, br0);   // prefetch layer-1 pair0
  layer0_mfma<6>(lds, av, b0f, a.b0[mlp], lane, wave);
  layer256<6, true, true, false>(lds, wt, wt + WT_SLOT, a.b1[mlp], lane, wave, nullptr, br0, br1);
  layer256<6, true, true, false>(lds, wt + WT_SLOT, wt + 2 * WT_SLOT, a.b2[mlp], lane, wave, nullptr, br0, br1);
  layer256<6, false, false, true>(lds, wt + 2 * WT_SLOT, wt + 2 * WT_SLOT, a.b3[mlp], lane, wave, mbuf, br0, br1);
  // per-column block max -> one atomic per column (max = commutative -> deterministic)
  atomicMax(a.gkeys + mlp * 256 + tid, fkey(mbuf[tid]));
}

// ------------------ patch membership / ordered compaction ------------------
__device__ __forceinline__ bool in_patch(const float* x, int r) {
  float a = x[r * 3], b = x[r * 3 + 1], c = x[r * 3 + 2];
  int c0 = min(max((int)floorf(a * 10.0f), 0), 9);
  int c1 = min(max((int)floorf(b * 10.0f), 0), 9);
  int c2 = min(max((int)floorf(c * 10.0f), 0), 9);
  return (c0 == 9) && (c1 == 9) && (c2 == 5);  // patch id 995
}
__global__ void K_count(const float* x, unsigned* counts) {
  __shared__ unsigned sw[4];
  int b = blockIdx.x, t = threadIdx.x;
  int base = b * 1024 + t * 4;
  unsigned c = 0;
#pragma unroll
  for (int j = 0; j < 4; ++j) c += in_patch(x, base + j) ? 1u : 0u;
#pragma unroll
  for (int o = 1; o < 64; o <<= 1) c += __shfl_xor((int)c, o, 64);
  if ((t & 63) == 0) sw[t >> 6] = c;
  __syncthreads();
  if (t == 0) counts[b] = sw[0] + sw[1] + sw[2] + sw[3];
}
__global__ void K_scan(const unsigned* counts, unsigned* bases) {
  __shared__ unsigned s[256];
  int t = threadIdx.x;
  unsigned c = counts[t];
  s[t] = c; __syncthreads();
  for (int o = 1; o < 256; o <<= 1) {
    unsigned v = (t >= o) ? s[t - o] : 0u;
    __syncthreads();
    s[t] += v;
    __syncthreads();
  }
  bases[t] = s[t] - c;
}
__global__ void K_fill(const float* x, const unsigned* bases, int* idx) {
  __shared__ unsigned s[256];
  int b = blockIdx.x, t = threadIdx.x;
  int base = b * 1024 + t * 4;
  unsigned fm = 0, c = 0;
#pragma unroll
  for (int j = 0; j < 4; ++j) {
    bool f = in_patch(x, base + j);
    fm |= (f ? 1u : 0u) << j;
    c += f ? 1u : 0u;
  }
  s[t] = c; __syncthreads();
  for (int o = 1; o < 256; o <<= 1) {
    unsigned v = (t >= o) ? s[t - o] : 0u;
    __syncthreads();
    s[t] += v;
    __syncthreads();
  }
  unsigned pos = bases[b] + s[t] - c;
#pragma unroll
  for (int j = 0; j < 4; ++j)
    if (fm & (1u << j)) idx[pos++] = base + j;
}

// ------------------ finalize params + broadcast part of o-layer1 (unscaled) ------------------
__global__ void K_vec(const unsigned* gkeys, const float* ow0, const float* ob0, float* vec0) {
  __shared__ float gp[256], lp[256];
  int t = threadIdx.x;
  gp[t] = unfkey(gkeys[t]);        // tb -> global_param
  lp[t] = unfkey(gkeys[256 + t]);  // br -> local_param
  __syncthreads();
  float acc = ob0[t];
  for (int k = 0; k < 256; ++k) {
    acc = fmaf(lp[k], ow0[(256 + k) * 256 + t], acc);
    acc = fmaf(gp[k], ow0[(512 + k) * 256 + t], acc);
  }
  vec0[t] = acc;
}

// ------------------ patch pipeline: tr-MLP + out-MLP + gt copy (unchanged from r12) ------------------
struct SmallArgs {
  const float* x; const float* y; const int* idx; int MM;
  const __bf16* wt;
  const float* trb0; const float* trb1; const float* trb2; const float* trb3;
  const float* vec0; const float* ob1; const float* ow2; const float* ob2;
  float* out;
};
__global__ __launch_bounds__(256, 2) void K_small(SmallArgs a) {
  __shared__ char lds[65536];
  int tid = threadIdx.x, lane = tid & 63, wave = tid >> 6;
  int pr0 = blockIdx.x << 7;
  const __bf16* wt6 = a.wt + (size_t)6 * WT_SLOT;
  const __bf16* w0f = a.wt + (size_t)11 * WT_SLOT + 2 * 8192;  // tr mini
  const int rlo = lane & 15;
  bf16x8 av[8];
  {  // gathered layer0 A-fragments in registers
#pragma unroll
    for (int rt = 0; rt < 8; ++rt) {
      bf16x8 v;
#pragma unroll
      for (int j = 0; j < 8; ++j) v[j] = (__bf16)0.f;
      if (lane < 16) {
        int j = a.idx[min(pr0 + rt * 16 + rlo, a.MM - 1)];
        v[0] = (__bf16)a.x[j * 3]; v[1] = (__bf16)a.x[j * 3 + 1]; v[2] = (__bf16)a.x[j * 3 + 2];
      }
      av[rt] = v;
    }
  }
  if (tid < 128 && pr0 + tid < a.MM) a.out[a.MM + pr0 + tid] = a.y[a.idx[pr0 + tid]];
  bf16x8 b0f[4];
#pragma unroll
  for (int i = 0; i < 4; ++i) b0f[i] = *(const bf16x8*)(w0f + (wave * 4 + i) * 512 + lane * 8);
  bf16x8 br0[8], br1[8];
  load_bpair(wt6, wave, lane, 0, br0);
  layer0_mfma<8>(lds, av, b0f, a.trb0, lane, wave);
  layer256<8, true, true, false>(lds, wt6, wt6 + WT_SLOT, a.trb1, lane, wave, nullptr, br0, br1);
  layer256<8, true, true, false>(lds, wt6 + WT_SLOT, wt6 + 2 * WT_SLOT, a.trb2, lane, wave, nullptr, br0, br1);
  layer256<8, false, true, false>(lds, wt6 + 2 * WT_SLOT, a.wt + (size_t)9 * WT_SLOT, a.trb3, lane, wave, nullptr, br0, br1);  // local_coord
  layer256<8, true, true, false>(lds, a.wt + (size_t)9 * WT_SLOT, a.wt + (size_t)10 * WT_SLOT, a.vec0, lane, wave, nullptr, br0, br1);  // o1
  layer256<8, true, true, false>(lds, a.wt + (size_t)10 * WT_SLOT, a.wt + (size_t)10 * WT_SLOT, a.ob1, lane, wave, nullptr, br0, br1);  // o2
  {  // o3: 256 -> 1 dot per row, fp32 out
    int r = tid >> 1, half = tid & 1, pr = pr0 + r;
    float s = 0.f;
    for (int i = 0; i < 128; ++i) {
      int c = (half << 7) + i;
      s = fmaf((float)*(const __bf16*)(lds + lds_off(r, 2 * c)), a.ow2[c], s);
    }
    s += __shfl_xor(s, 1, 64);
    if (half == 0 && pr < a.MM) a.out[pr] = s + a.ob2[0];
  }
}

extern "C" void kernel_launch(void* const* d_in, const int* in_sizes, int n_in,
                              void* d_out, int out_size, void* d_ws, size_t ws_size,
                              hipStream_t stream) {
  const float* x = (const float*)d_in[0];
  const float* y = (const float*)d_in[1];
  char* ws = (char*)d_ws;
  unsigned* gkeys = (unsigned*)(ws + WS_GKEYS);
  float* vec0 = (float*)(ws + WS_VEC0);
  unsigned* counts = (unsigned*)(ws + WS_COUNTS);
  unsigned* bases = (unsigned*)(ws + WS_BASES);
  int* idx = (int*)(ws + WS_IDX);
  __bf16* wt = (__bf16*)(ws + WS_WT);
  int MM = out_size / 2;

  ConvArgs ca;
  for (int m = 0; m < 3; ++m)           // 0=tb,1=br,2=tr ; L -> w_{L+1}
    for (int L = 0; L < 3; ++L)
      ca.src[m * 3 + L] = (const float*)d_in[2 + m * 8 + 2 * (L + 1)];
  ca.src[9] = (const float*)d_in[26];   // o_w0 (top 256 rows used)
  ca.src[10] = (const float*)d_in[28];  // o_w1
  ca.src[11] = (const float*)d_in[2];   // tb_w0 (3x256)
  ca.src[12] = (const float*)d_in[10];  // br_w0
  ca.src[13] = (const float*)d_in[18];  // tr_w0
  hipLaunchKernelGGL(K_conv, dim3(15, 16), dim3(256), 0, stream, ca, wt, gkeys);

  K_count<<<256, 256, 0, stream>>>(x, counts);
  K_scan<<<1, 256, 0, stream>>>(counts, bases);
  K_fill<<<256, 256, 0, stream>>>(x, bases, idx);

  BigArgs ba;
  ba.x = x; ba.wt = wt; ba.gkeys = gkeys;
  ba.b0[0] = (const float*)d_in[3];  ba.b1[0] = (const float*)d_in[5];
  ba.b2[0] = (const float*)d_in[7];  ba.b3[0] = (const float*)d_in[9];
  ba.b0[1] = (const float*)d_in[11]; ba.b1[1] = (const float*)d_in[13];
  ba.b2[1] = (const float*)d_in[15]; ba.b3[1] = (const float*)d_in[17];
  K_big<<<dim3((NPTS + 95) / 96, 2), 256, 0, stream>>>(ba);

  K_vec<<<1, 256, 0, stream>>>(gkeys, (const float*)d_in[26], (const float*)d_in[27], vec0);

  if (MM > 0) {
    SmallArgs sa;
    sa.x = x; sa.y = y; sa.idx = idx; sa.MM = MM; sa.wt = wt;
    sa.trb0 = (const float*)d_in[19]; sa.trb1 = (const float*)d_in[21];
    sa.trb2 = (const float*)d_in[23]; sa.trb3 = (const float*)d_in[25];
    sa.vec0 = vec0;
    sa.ob1 = (const float*)d_in[29];
    sa.ow2 = (const float*)d_in[30]; sa.ob2 = (const float*)d_in[31];
    sa.out = (float*)d_out;
    K_small<<<(MM + 127) / 128, 256, 0, stream>>>(sa);
  }
}

// Round 14
// 273.522 us; speedup vs baseline: 1.2154x; 1.2154x over previous
//
#include <hip/hip_runtime.h>

typedef __bf16 bf16x8 __attribute__((ext_vector_type(8)));
typedef float f32x4 __attribute__((ext_vector_type(4)));

#define WT_SLOT 65536              // elements per 256x256 bf16 weight slot (packed fragment order)
#define WS_GKEYS 0                 // 512 u32 (tb keys, br keys)
#define WS_VEC0  4096              // 256 f32
#define WS_COUNTS 8192             // 256 u32
#define WS_BASES 12288             // 256 u32
#define WS_IDX   16384             // 4096 i32
#define WS_WT    32768             // 12 slots * 131072 B (slot 11 = 3 packed-W0 minis)

#define TANH_K 2.8853900817779268f   // 2*log2(e); tanh layers have W,b pre-scaled by this
#define NPTS 262144

__device__ __forceinline__ unsigned fkey(float f) {
  unsigned u = __float_as_uint(f);
  return (u & 0x80000000u) ? ~u : (u | 0x80000000u);
}
__device__ __forceinline__ float unfkey(unsigned k) {
  unsigned u = (k & 0x80000000u) ? (k & 0x7FFFFFFFu) : ~k;
  return __uint_as_float(u);
}
// swizzled LDS byte offset for act tiles, row stride 512B.
// (r&15) spread: the 16 rows co-read by a 16-lane quarter hit 16 distinct 16B slots.
__device__ __forceinline__ int lds_off(int r, int cb) {
  return r * 512 + (cb ^ ((r & 15) << 4));
}
// tanh from pre-scaled input t = 2log2e*x : 1 - 2/(exp2(t)+1)
__device__ __forceinline__ float tanh_scaled(float t) {
  float e = __builtin_amdgcn_exp2f(t);
  return fmaf(__builtin_amdgcn_rcpf(e + 1.0f), -2.0f, 1.0f);
}
// T12-verified packed bf16 convert (2 f32 -> 1 u32)
__device__ __forceinline__ unsigned cvt_pk_bf16(float lo, float hi) {
  unsigned d;
  asm("v_cvt_pk_bf16_f32 %0, %1, %2" : "=v"(d) : "v"(lo), "v"(hi));
  return d;
}

// Packed B layout: element (n = nt*16 + (l&15), k = ks*32 + (l>>4)*8 + j) at
// linear ks*8192 + nt*512 + l*8 + j. Wave w (of 4) owns nt = 4w..4w+3 (cols 64w..64w+63).
// Single-ks quad load: 4 fragments = 16 VGPRs (halves live B-regs vs the old pair scheme).
__device__ __forceinline__ void load_bquad(const __bf16* wt, int wave, int lane, int p,
                                           bf16x8 b[4]) {
  const __bf16* base = wt + p * 8192 + wave * 2048 + lane * 8;
#pragma unroll
  for (int i = 0; i < 4; ++i)
    b[i] = *(const bf16x8*)(base + i * 512);
}

// Swapped-operand MFMA: mfma(W_frag, A_frag, acc) -> lane holds rows rt*16+(lane&15),
// cols cbase + (lane>>4)*4 + rg (4 consecutive). NRT = row-tiles in the act tile.
template <int NRT>
__device__ __forceinline__ void compute_quad(char* lds, const bf16x8 bc[4], int ks,
                                             int rlo, int khi2, f32x4 acc[NRT][4]) {
  __builtin_amdgcn_s_setprio(1);
  int cb = ks * 64 + khi2;   // byte column of this k-chunk
#pragma unroll
  for (int rt = 0; rt < NRT; ++rt) {
    bf16x8 av = *(const bf16x8*)(lds + lds_off(rt * 16 + rlo, cb));
#pragma unroll
    for (int i = 0; i < 4; ++i)
      acc[rt][i] = __builtin_amdgcn_mfma_f32_16x16x32_bf16(bc[i], av, acc[rt][i], 0, 0, 0);
  }
  __builtin_amdgcn_s_setprio(0);
}

// bias is already inside acc (C-operand init); epilogue = activation + pack + store.
template <int NRT, bool TANH, bool WRITE, bool CMAX>
__device__ __forceinline__ void epilogue(char* lds, int lane, int wave,
                                         f32x4 acc[NRT][4], float* mbuf) {
  const int rlo = lane & 15;
  const int q4 = (lane >> 4) << 2;
#pragma unroll
  for (int i = 0; i < 4; ++i) {
    const int cbase = (wave * 4 + i) * 16 + q4;       // 4 consecutive cols per lane
    f32x4 cm;
#pragma unroll
    for (int rt = 0; rt < NRT; ++rt) {
      f32x4 v;
#pragma unroll
      for (int rg = 0; rg < 4; ++rg) {
        float t = acc[rt][i][rg];
        if (TANH) t = tanh_scaled(t);
        v[rg] = t;
      }
      if (WRITE) {
        uint2 pv;
        pv.x = cvt_pk_bf16(v[0], v[1]);
        pv.y = cvt_pk_bf16(v[2], v[3]);
        *(uint2*)(lds + lds_off(rt * 16 + rlo, 2 * cbase)) = pv;
      }
      if (CMAX) {
        if (rt == 0) cm = v;
        else {
#pragma unroll
          for (int rg = 0; rg < 4; ++rg) cm[rg] = fmaxf(cm[rg], v[rg]);
        }
      }
    }
    if (CMAX) {  // reduce over rows (lane&15 across lanes), cols distinct per (q,rg)
#pragma unroll
      for (int rg = 0; rg < 4; ++rg) {
#pragma unroll
        for (int off = 1; off <= 8; off <<= 1)
          cm[rg] = fmaxf(cm[rg], __shfl_xor(cm[rg], off, 64));
      }
      if (rlo == 0) *(f32x4*)(mbuf + cbase) = cm;
    }
  }
}

// acc init = bias (x TANH_K for tanh layers, whose W is pre-scaled likewise)
template <int NRT, bool TANH>
__device__ __forceinline__ void acc_init(f32x4 acc[NRT][4], const float* bias, int lane, int wave) {
  const int q4 = (lane >> 4) << 2;
#pragma unroll
  for (int i = 0; i < 4; ++i) {
    f32x4 bv = *(const f32x4*)(bias + (wave * 4 + i) * 16 + q4);
    if (TANH) {
#pragma unroll
      for (int rg = 0; rg < 4; ++rg) bv[rg] *= TANH_K;
    }
#pragma unroll
    for (int rt = 0; rt < NRT; ++rt) acc[rt][i] = bv;
  }
}

// One 256->256 layer, single-ks double-buffered B. Precondition: b0 holds THIS layer's
// ks0 quad. Postcondition: b0 holds wt_next's ks0 quad.
// CMAX-only layers (WRITE=false) skip the pre-epilogue barrier (no act-tile stores).
template <int NRT, bool TANH, bool WRITE, bool CMAX>
__device__ __forceinline__ void layer256(char* lds, const __bf16* wt, const __bf16* wt_next,
                                         const float* bias, int lane, int wave, float* mbuf,
                                         bf16x8 b0[4], bf16x8 b1[4]) {
  const int rlo = lane & 15;
  const int khi2 = (lane >> 4) << 4;   // byte offset of k-subrange
  f32x4 acc[NRT][4];
  acc_init<NRT, TANH>(acc, bias, lane, wave);

  load_bquad(wt, wave, lane, 1, b1);
  compute_quad<NRT>(lds, b0, 0, rlo, khi2, acc);
  load_bquad(wt, wave, lane, 2, b0);
  compute_quad<NRT>(lds, b1, 1, rlo, khi2, acc);
  load_bquad(wt, wave, lane, 3, b1);
  compute_quad<NRT>(lds, b0, 2, rlo, khi2, acc);
  load_bquad(wt, wave, lane, 4, b0);
  compute_quad<NRT>(lds, b1, 3, rlo, khi2, acc);
  load_bquad(wt, wave, lane, 5, b1);
  compute_quad<NRT>(lds, b0, 4, rlo, khi2, acc);
  load_bquad(wt, wave, lane, 6, b0);
  compute_quad<NRT>(lds, b1, 5, rlo, khi2, acc);
  load_bquad(wt, wave, lane, 7, b1);
  compute_quad<NRT>(lds, b0, 6, rlo, khi2, acc);
  load_bquad(wt_next, wave, lane, 0, b0);   // prefetch next layer's ks0
  compute_quad<NRT>(lds, b1, 7, rlo, khi2, acc);

  if (WRITE) __syncthreads();               // act-tile reads done before overwrite
  epilogue<NRT, TANH, WRITE, CMAX>(lds, lane, wave, acc, mbuf);
  __syncthreads();
}

// layer0 (K=32) via MFMA; A-fragments (av) built in registers by the caller:
// lane<16 holds {x0,x1,x2,0...} for row rt*16+(lane&15); lanes>=16 all-zero.
template <int NRT>
__device__ __forceinline__ void layer0_mfma(char* lds, const bf16x8* av, const bf16x8 b0f[4],
                                            const float* bias, int lane, int wave) {
  f32x4 acc[NRT][4];
  acc_init<NRT, true>(acc, bias, lane, wave);
  __builtin_amdgcn_s_setprio(1);
#pragma unroll
  for (int rt = 0; rt < NRT; ++rt) {
#pragma unroll
    for (int i = 0; i < 4; ++i)
      acc[rt][i] = __builtin_amdgcn_mfma_f32_16x16x32_bf16(b0f[i], av[rt], acc[rt][i], 0, 0, 0);
  }
  __builtin_amdgcn_s_setprio(0);
  epilogue<NRT, true, true, false>(lds, lane, wave, acc, nullptr);
  __syncthreads();
}

// ------------------ weight convert/transpose/pack to bf16 (tanh layers pre-scaled) ------------------
struct ConvArgs { const float* src[14]; };
__global__ void K_conv(ConvArgs a, __bf16* wt, unsigned* gkeys) {
  int job = blockIdx.x, t = threadIdx.x, y = blockIdx.y;
  if (job == 14) {
    if (y == 0) { gkeys[t] = 0u; gkeys[256 + t] = 0u; }
    return;
  }
  if (job >= 11) {  // W0 minis: (3,256) fp32 -> one K=32 fragment chunk, zero-padded, tanh-scaled
    if (y >= 2) return;
    const float* s = a.src[job];
    __bf16* d = wt + (size_t)11 * WT_SLOT + (job - 11) * 8192;
#pragma unroll
    for (int it = 0; it < 16; ++it) {
      int p = y * 4096 + it * 256 + t;
      int nt = (p >> 9) & 15, ln = (p >> 3) & 63, j = p & 7;
      int n = nt * 16 + (ln & 15);
      int k = ((ln >> 4) << 3) + j;
      d[p] = (k < 3) ? (__bf16)(TANH_K * s[k * 256 + n]) : (__bf16)0.f;
    }
    return;
  }
  // jobs 0..10: tanh layers (all except job%3==2 within 0..8) scaled by TANH_K
  const float scale = (job >= 9 || (job % 3) != 2) ? TANH_K : 1.0f;
  const float* s = a.src[job];
  __bf16* d = wt + (size_t)job * WT_SLOT;
#pragma unroll
  for (int it = 0; it < 16; ++it) {
    int p = y * 4096 + it * 256 + t;                 // packed linear index
    int ks = p >> 13, nt = (p >> 9) & 15, ln = (p >> 3) & 63, j = p & 7;
    int n = nt * 16 + (ln & 15);
    int k = ks * 32 + ((ln >> 4) << 3) + j;
    d[p] = (__bf16)(scale * s[(k << 8) | n]);        // src is [K][N] fp32 (first 256 rows)
  }
}

// ------------------ big fused MLP (tb & br) + column max: 64-row tiles, 3 blocks/CU ------------------
struct BigArgs {
  const float* x;
  const __bf16* wt;
  const float* b0[2]; const float* b1[2]; const float* b2[2]; const float* b3[2];
  unsigned* gkeys;
};
__global__ __launch_bounds__(256, 3) void K_big(BigArgs a) {
  __shared__ char lds[32768];          // 64-row act tile
  __shared__ float mbuf[256];
  int tid = threadIdx.x, lane = tid & 63, wave = tid >> 6;
  int mlp = blockIdx.y;
  int row0 = blockIdx.x << 6;          // 64 rows per block; 64 | NPTS exactly
  const __bf16* wt = a.wt + (size_t)(mlp * 3) * WT_SLOT;
  const __bf16* w0f = a.wt + (size_t)11 * WT_SLOT + mlp * 8192;
  // layer0 A-fragments in registers (no LDS staging)
  const int rlo = lane & 15;
  bf16x8 av[4];
  {
    const float* xr = a.x + (size_t)row0 * 3;
#pragma unroll
    for (int rt = 0; rt < 4; ++rt) {
      bf16x8 v;
#pragma unroll
      for (int j = 0; j < 8; ++j) v[j] = (__bf16)0.f;
      if (lane < 16) {
        const float* p = xr + (rt * 16 + rlo) * 3;
        v[0] = (__bf16)p[0]; v[1] = (__bf16)p[1]; v[2] = (__bf16)p[2];
      }
      av[rt] = v;
    }
  }
  bf16x8 b0f[4];
#pragma unroll
  for (int i = 0; i < 4; ++i) b0f[i] = *(const bf16x8*)(w0f + (wave * 4 + i) * 512 + lane * 8);
  bf16x8 br0[4], br1[4];
  load_bquad(wt, wave, lane, 0, br0);   // prefetch layer-1 ks0
  layer0_mfma<4>(lds, av, b0f, a.b0[mlp], lane, wave);
  layer256<4, true, true, false>(lds, wt, wt + WT_SLOT, a.b1[mlp], lane, wave, nullptr, br0, br1);
  layer256<4, true, true, false>(lds, wt + WT_SLOT, wt + 2 * WT_SLOT, a.b2[mlp], lane, wave, nullptr, br0, br1);
  layer256<4, false, false, true>(lds, wt + 2 * WT_SLOT, wt + 2 * WT_SLOT, a.b3[mlp], lane, wave, mbuf, br0, br1);
  // per-column block max -> one atomic per column (max = commutative -> deterministic)
  atomicMax(a.gkeys + mlp * 256 + tid, fkey(mbuf[tid]));
}

// ------------------ patch membership / ordered compaction ------------------
__device__ __forceinline__ bool in_patch(const float* x, int r) {
  float a = x[r * 3], b = x[r * 3 + 1], c = x[r * 3 + 2];
  int c0 = min(max((int)floorf(a * 10.0f), 0), 9);
  int c1 = min(max((int)floorf(b * 10.0f), 0), 9);
  int c2 = min(max((int)floorf(c * 10.0f), 0), 9);
  return (c0 == 9) && (c1 == 9) && (c2 == 5);  // patch id 995
}
__global__ void K_count(const float* x, unsigned* counts) {
  __shared__ unsigned sw[4];
  int b = blockIdx.x, t = threadIdx.x;
  int base = b * 1024 + t * 4;
  unsigned c = 0;
#pragma unroll
  for (int j = 0; j < 4; ++j) c += in_patch(x, base + j) ? 1u : 0u;
#pragma unroll
  for (int o = 1; o < 64; o <<= 1) c += __shfl_xor((int)c, o, 64);
  if ((t & 63) == 0) sw[t >> 6] = c;
  __syncthreads();
  if (t == 0) counts[b] = sw[0] + sw[1] + sw[2] + sw[3];
}
__global__ void K_scan(const unsigned* counts, unsigned* bases) {
  __shared__ unsigned s[256];
  int t = threadIdx.x;
  unsigned c = counts[t];
  s[t] = c; __syncthreads();
  for (int o = 1; o < 256; o <<= 1) {
    unsigned v = (t >= o) ? s[t - o] : 0u;
    __syncthreads();
    s[t] += v;
    __syncthreads();
  }
  bases[t] = s[t] - c;
}
__global__ void K_fill(const float* x, const unsigned* bases, int* idx) {
  __shared__ unsigned s[256];
  int b = blockIdx.x, t = threadIdx.x;
  int base = b * 1024 + t * 4;
  unsigned fm = 0, c = 0;
#pragma unroll
  for (int j = 0; j < 4; ++j) {
    bool f = in_patch(x, base + j);
    fm |= (f ? 1u : 0u) << j;
    c += f ? 1u : 0u;
  }
  s[t] = c; __syncthreads();
  for (int o = 1; o < 256; o <<= 1) {
    unsigned v = (t >= o) ? s[t - o] : 0u;
    __syncthreads();
    s[t] += v;
    __syncthreads();
  }
  unsigned pos = bases[b] + s[t] - c;
#pragma unroll
  for (int j = 0; j < 4; ++j)
    if (fm & (1u << j)) idx[pos++] = base + j;
}

// ------------------ finalize params + broadcast part of o-layer1 (unscaled) ------------------
__global__ void K_vec(const unsigned* gkeys, const float* ow0, const float* ob0, float* vec0) {
  __shared__ float gp[256], lp[256];
  int t = threadIdx.x;
  gp[t] = unfkey(gkeys[t]);        // tb -> global_param
  lp[t] = unfkey(gkeys[256 + t]);  // br -> local_param
  __syncthreads();
  float acc = ob0[t];
  for (int k = 0; k < 256; ++k) {
    acc = fmaf(lp[k], ow0[(256 + k) * 256 + t], acc);
    acc = fmaf(gp[k], ow0[(512 + k) * 256 + t], acc);
  }
  vec0[t] = acc;
}

// ------------------ patch pipeline: tr-MLP + out-MLP + gt copy (structure unchanged) ------------------
struct SmallArgs {
  const float* x; const float* y; const int* idx; int MM;
  const __bf16* wt;
  const float* trb0; const float* trb1; const float* trb2; const float* trb3;
  const float* vec0; const float* ob1; const float* ow2; const float* ob2;
  float* out;
};
__global__ __launch_bounds__(256, 2) void K_small(SmallArgs a) {
  __shared__ char lds[65536];
  int tid = threadIdx.x, lane = tid & 63, wave = tid >> 6;
  int pr0 = blockIdx.x << 7;
  const __bf16* wt6 = a.wt + (size_t)6 * WT_SLOT;
  const __bf16* w0f = a.wt + (size_t)11 * WT_SLOT + 2 * 8192;  // tr mini
  const int rlo = lane & 15;
  bf16x8 av[8];
  {  // gathered layer0 A-fragments in registers
#pragma unroll
    for (int rt = 0; rt < 8; ++rt) {
      bf16x8 v;
#pragma unroll
      for (int j = 0; j < 8; ++j) v[j] = (__bf16)0.f;
      if (lane < 16) {
        int j = a.idx[min(pr0 + rt * 16 + rlo, a.MM - 1)];
        v[0] = (__bf16)a.x[j * 3]; v[1] = (__bf16)a.x[j * 3 + 1]; v[2] = (__bf16)a.x[j * 3 + 2];
      }
      av[rt] = v;
    }
  }
  if (tid < 128 && pr0 + tid < a.MM) a.out[a.MM + pr0 + tid] = a.y[a.idx[pr0 + tid]];
  bf16x8 b0f[4];
#pragma unroll
  for (int i = 0; i < 4; ++i) b0f[i] = *(const bf16x8*)(w0f + (wave * 4 + i) * 512 + lane * 8);
  bf16x8 br0[4], br1[4];
  load_bquad(wt6, wave, lane, 0, br0);
  layer0_mfma<8>(lds, av, b0f, a.trb0, lane, wave);
  layer256<8, true, true, false>(lds, wt6, wt6 + WT_SLOT, a.trb1, lane, wave, nullptr, br0, br1);
  layer256<8, true, true, false>(lds, wt6 + WT_SLOT, wt6 + 2 * WT_SLOT, a.trb2, lane, wave, nullptr, br0, br1);
  layer256<8, false, true, false>(lds, wt6 + 2 * WT_SLOT, a.wt + (size_t)9 * WT_SLOT, a.trb3, lane, wave, nullptr, br0, br1);  // local_coord
  layer256<8, true, true, false>(lds, a.wt + (size_t)9 * WT_SLOT, a.wt + (size_t)10 * WT_SLOT, a.vec0, lane, wave, nullptr, br0, br1);  // o1
  layer256<8, true, true, false>(lds, a.wt + (size_t)10 * WT_SLOT, a.wt + (size_t)10 * WT_SLOT, a.ob1, lane, wave, nullptr, br0, br1);  // o2
  {  // o3: 256 -> 1 dot per row, fp32 out
    int r = tid >> 1, half = tid & 1, pr = pr0 + r;
    float s = 0.f;
    for (int i = 0; i < 128; ++i) {
      int c = (half << 7) + i;
      s = fmaf((float)*(const __bf16*)(lds + lds_off(r, 2 * c)), a.ow2[c], s);
    }
    s += __shfl_xor(s, 1, 64);
    if (half == 0 && pr < a.MM) a.out[pr] = s + a.ob2[0];
  }
}

extern "C" void kernel_launch(void* const* d_in, const int* in_sizes, int n_in,
                              void* d_out, int out_size, void* d_ws, size_t ws_size,
                              hipStream_t stream) {
  const float* x = (const float*)d_in[0];
  const float* y = (const float*)d_in[1];
  char* ws = (char*)d_ws;
  unsigned* gkeys = (unsigned*)(ws + WS_GKEYS);
  float* vec0 = (float*)(ws + WS_VEC0);
  unsigned* counts = (unsigned*)(ws + WS_COUNTS);
  unsigned* bases = (unsigned*)(ws + WS_BASES);
  int* idx = (int*)(ws + WS_IDX);
  __bf16* wt = (__bf16*)(ws + WS_WT);
  int MM = out_size / 2;

  ConvArgs ca;
  for (int m = 0; m < 3; ++m)           // 0=tb,1=br,2=tr ; L -> w_{L+1}
    for (int L = 0; L < 3; ++L)
      ca.src[m * 3 + L] = (const float*)d_in[2 + m * 8 + 2 * (L + 1)];
  ca.src[9] = (const float*)d_in[26];   // o_w0 (top 256 rows used)
  ca.src[10] = (const float*)d_in[28];  // o_w1
  ca.src[11] = (const float*)d_in[2];   // tb_w0 (3x256)
  ca.src[12] = (const float*)d_in[10];  // br_w0
  ca.src[13] = (const float*)d_in[18];  // tr_w0
  hipLaunchKernelGGL(K_conv, dim3(15, 16), dim3(256), 0, stream, ca, wt, gkeys);

  K_count<<<256, 256, 0, stream>>>(x, counts);
  K_scan<<<1, 256, 0, stream>>>(counts, bases);
  K_fill<<<256, 256, 0, stream>>>(x, bases, idx);

  BigArgs ba;
  ba.x = x; ba.wt = wt; ba.gkeys = gkeys;
  ba.b0[0] = (const float*)d_in[3];  ba.b1[0] = (const float*)d_in[5];
  ba.b2[0] = (const float*)d_in[7];  ba.b3[0] = (const float*)d_in[9];
  ba.b0[1] = (const float*)d_in[11]; ba.b1[1] = (const float*)d_in[13];
  ba.b2[1] = (const float*)d_in[15]; ba.b3[1] = (const float*)d_in[17];
  K_big<<<dim3(NPTS / 64, 2), 256, 0, stream>>>(ba);

  K_vec<<<1, 256, 0, stream>>>(gkeys, (const float*)d_in[26], (const float*)d_in[27], vec0);

  if (MM > 0) {
    SmallArgs sa;
    sa.x = x; sa.y = y; sa.idx = idx; sa.MM = MM; sa.wt = wt;
    sa.trb0 = (const float*)d_in[19]; sa.trb1 = (const float*)d_in[21];
    sa.trb2 = (const float*)d_in[23]; sa.trb3 = (const float*)d_in[25];
    sa.vec0 = vec0;
    sa.ob1 = (const float*)d_in[29];
    sa.ow2 = (const float*)d_in[30]; sa.ob2 = (const float*)d_in[31];
    sa.out = (float*)d_out;
    K_small<<<(MM + 127) / 128, 256, 0, stream>>>(sa);
  }
}

// Round 15
// 272.170 us; speedup vs baseline: 1.2215x; 1.0050x over previous
//
#include <hip/hip_runtime.h>

typedef __bf16 bf16x8 __attribute__((ext_vector_type(8)));
typedef float f32x4 __attribute__((ext_vector_type(4)));

#define WT_SLOT 65536              // elements per 256x256 bf16 weight slot (packed fragment order)
#define WS_GKEYS 0                 // 512 u32 (tb keys, br keys)
#define WS_VEC0  4096              // 256 f32
#define WS_COUNTS 8192             // 256 u32
#define WS_BASES 12288             // 256 u32
#define WS_IDX   16384             // 4096 i32
#define WS_WT    32768             // 12 slots * 131072 B (slot 11 = 3 packed-W0 minis)

#define TANH_K 2.8853900817779268f   // 2*log2(e); tanh layers have W,b pre-scaled by this
#define NPTS 262144

__device__ __forceinline__ unsigned fkey(float f) {
  unsigned u = __float_as_uint(f);
  return (u & 0x80000000u) ? ~u : (u | 0x80000000u);
}
__device__ __forceinline__ float unfkey(unsigned k) {
  unsigned u = (k & 0x80000000u) ? (k & 0x7FFFFFFFu) : ~k;
  return __uint_as_float(u);
}
// swizzled LDS byte offset for act tiles, row stride 512B.
__device__ __forceinline__ int lds_off(int r, int cb) {
  return r * 512 + (cb ^ ((r & 15) << 4));
}
// tanh from pre-scaled input t = 2log2e*x : 1 - 2/(exp2(t)+1)
__device__ __forceinline__ float tanh_scaled(float t) {
  float e = __builtin_amdgcn_exp2f(t);
  return fmaf(__builtin_amdgcn_rcpf(e + 1.0f), -2.0f, 1.0f);
}
// T12-verified packed bf16 convert (2 f32 -> 1 u32)
__device__ __forceinline__ unsigned cvt_pk_bf16(float lo, float hi) {
  unsigned d;
  asm("v_cvt_pk_bf16_f32 %0, %1, %2" : "=v"(d) : "v"(lo), "v"(hi));
  return d;
}

// Packed B layout: element (n = nt*16 + (l&15), k = ks*32 + (l>>4)*8 + j) at
// linear ks*8192 + nt*512 + l*8 + j. Wave w (of 4) owns nt = 4w..4w+3 (cols 64w..64w+63).
// quad load: one ks (4 fragments, 16 VGPR). pair load: two ks (8 fragments, 32 VGPR).
__device__ __forceinline__ void load_bquad(const __bf16* wt, int wave, int lane, int p,
                                           bf16x8 b[4]) {
  const __bf16* base = wt + p * 8192 + wave * 2048 + lane * 8;
#pragma unroll
  for (int i = 0; i < 4; ++i)
    b[i] = *(const bf16x8*)(base + i * 512);
}
__device__ __forceinline__ void load_bpair(const __bf16* wt, int wave, int lane, int p,
                                           bf16x8 b[8]) {
  const __bf16* base = wt + p * 16384 + wave * 2048 + lane * 8;
#pragma unroll
  for (int h = 0; h < 2; ++h)
#pragma unroll
    for (int i = 0; i < 4; ++i)
      b[h * 4 + i] = *(const bf16x8*)(base + h * 8192 + i * 512);
}

// Swapped-operand MFMA: mfma(W_frag, A_frag, acc) -> lane holds rows rt*16+(lane&15),
// cols cbase + (lane>>4)*4 + rg (4 consecutive). NRT = row-tiles in the act tile.
template <int NRT>
__device__ __forceinline__ void compute_quad(char* lds, const bf16x8 bc[4], int ks,
                                             int rlo, int khi2, f32x4 acc[NRT][4]) {
  __builtin_amdgcn_s_setprio(1);
  int cb = ks * 64 + khi2;
#pragma unroll
  for (int rt = 0; rt < NRT; ++rt) {
    bf16x8 av = *(const bf16x8*)(lds + lds_off(rt * 16 + rlo, cb));
#pragma unroll
    for (int i = 0; i < 4; ++i)
      acc[rt][i] = __builtin_amdgcn_mfma_f32_16x16x32_bf16(bc[i], av, acc[rt][i], 0, 0, 0);
  }
  __builtin_amdgcn_s_setprio(0);
}
template <int NRT>
__device__ __forceinline__ void compute_pair(char* lds, const bf16x8 bc[8], int ksbase,
                                             int rlo, int khi2, f32x4 acc[NRT][4]) {
  __builtin_amdgcn_s_setprio(1);
#pragma unroll
  for (int h = 0; h < 2; ++h) {
    int cb = (ksbase + h) * 64 + khi2;
#pragma unroll
    for (int rt = 0; rt < NRT; ++rt) {
      bf16x8 av = *(const bf16x8*)(lds + lds_off(rt * 16 + rlo, cb));
#pragma unroll
      for (int i = 0; i < 4; ++i)
        acc[rt][i] = __builtin_amdgcn_mfma_f32_16x16x32_bf16(bc[h * 4 + i], av, acc[rt][i], 0, 0, 0);
    }
  }
  __builtin_amdgcn_s_setprio(0);
}

// bias is already inside acc (C-operand init); epilogue = activation + pack + store.
template <int NRT, bool TANH, bool WRITE, bool CMAX>
__device__ __forceinline__ void epilogue(char* lds, int lane, int wave,
                                         f32x4 acc[NRT][4], float* mbuf) {
  const int rlo = lane & 15;
  const int q4 = (lane >> 4) << 2;
#pragma unroll
  for (int i = 0; i < 4; ++i) {
    const int cbase = (wave * 4 + i) * 16 + q4;       // 4 consecutive cols per lane
    f32x4 cm;
#pragma unroll
    for (int rt = 0; rt < NRT; ++rt) {
      f32x4 v;
#pragma unroll
      for (int rg = 0; rg < 4; ++rg) {
        float t = acc[rt][i][rg];
        if (TANH) t = tanh_scaled(t);
        v[rg] = t;
      }
      if (WRITE) {
        uint2 pv;
        pv.x = cvt_pk_bf16(v[0], v[1]);
        pv.y = cvt_pk_bf16(v[2], v[3]);
        *(uint2*)(lds + lds_off(rt * 16 + rlo, 2 * cbase)) = pv;
      }
      if (CMAX) {
        if (rt == 0) cm = v;
        else {
#pragma unroll
          for (int rg = 0; rg < 4; ++rg) cm[rg] = fmaxf(cm[rg], v[rg]);
        }
      }
    }
    if (CMAX) {  // reduce over rows (lane&15 across lanes), cols distinct per (q,rg)
#pragma unroll
      for (int rg = 0; rg < 4; ++rg) {
#pragma unroll
        for (int off = 1; off <= 8; off <<= 1)
          cm[rg] = fmaxf(cm[rg], __shfl_xor(cm[rg], off, 64));
      }
      if (rlo == 0) *(f32x4*)(mbuf + cbase) = cm;
    }
  }
}

// acc init = bias (x TANH_K for tanh layers, whose W is pre-scaled likewise)
template <int NRT, bool TANH>
__device__ __forceinline__ void acc_init(f32x4 acc[NRT][4], const float* bias, int lane, int wave) {
  const int q4 = (lane >> 4) << 2;
#pragma unroll
  for (int i = 0; i < 4; ++i) {
    f32x4 bv = *(const f32x4*)(bias + (wave * 4 + i) * 16 + q4);
    if (TANH) {
#pragma unroll
      for (int rg = 0; rg < 4; ++rg) bv[rg] *= TANH_K;
    }
#pragma unroll
    for (int rt = 0; rt < NRT; ++rt) acc[rt][i] = bv;
  }
}

// One 256->256 layer, quad-buffered B (r14-verified; used by K_big).
template <int NRT, bool TANH, bool WRITE, bool CMAX>
__device__ __forceinline__ void layer256_quad(char* lds, const __bf16* wt, const __bf16* wt_next,
                                              const float* bias, int lane, int wave, float* mbuf,
                                              bf16x8 b0[4], bf16x8 b1[4]) {
  const int rlo = lane & 15;
  const int khi2 = (lane >> 4) << 4;
  f32x4 acc[NRT][4];
  acc_init<NRT, TANH>(acc, bias, lane, wave);

  load_bquad(wt, wave, lane, 1, b1);
  compute_quad<NRT>(lds, b0, 0, rlo, khi2, acc);
  load_bquad(wt, wave, lane, 2, b0);
  compute_quad<NRT>(lds, b1, 1, rlo, khi2, acc);
  load_bquad(wt, wave, lane, 3, b1);
  compute_quad<NRT>(lds, b0, 2, rlo, khi2, acc);
  load_bquad(wt, wave, lane, 4, b0);
  compute_quad<NRT>(lds, b1, 3, rlo, khi2, acc);
  load_bquad(wt, wave, lane, 5, b1);
  compute_quad<NRT>(lds, b0, 4, rlo, khi2, acc);
  load_bquad(wt, wave, lane, 6, b0);
  compute_quad<NRT>(lds, b1, 5, rlo, khi2, acc);
  load_bquad(wt, wave, lane, 7, b1);
  compute_quad<NRT>(lds, b0, 6, rlo, khi2, acc);
  load_bquad(wt_next, wave, lane, 0, b0);
  compute_quad<NRT>(lds, b1, 7, rlo, khi2, acc);

  if (WRITE) __syncthreads();
  epilogue<NRT, TANH, WRITE, CMAX>(lds, lane, wave, acc, mbuf);
  __syncthreads();
}

// One 256->256 layer, pair-buffered B (r12-verified schedule; used by K_small).
template <int NRT, bool TANH, bool WRITE, bool CMAX>
__device__ __forceinline__ void layer256_pair(char* lds, const __bf16* wt, const __bf16* wt_next,
                                              const float* bias, int lane, int wave, float* mbuf,
                                              bf16x8 b0[8], bf16x8 b1[8]) {
  const int rlo = lane & 15;
  const int khi2 = (lane >> 4) << 4;
  f32x4 acc[NRT][4];
  acc_init<NRT, TANH>(acc, bias, lane, wave);

  load_bpair(wt, wave, lane, 1, b1);
  compute_pair<NRT>(lds, b0, 0, rlo, khi2, acc);
  load_bpair(wt, wave, lane, 2, b0);
  compute_pair<NRT>(lds, b1, 2, rlo, khi2, acc);
  load_bpair(wt, wave, lane, 3, b1);
  compute_pair<NRT>(lds, b0, 4, rlo, khi2, acc);
  load_bpair(wt_next, wave, lane, 0, b0);
  compute_pair<NRT>(lds, b1, 6, rlo, khi2, acc);

  if (WRITE) __syncthreads();
  epilogue<NRT, TANH, WRITE, CMAX>(lds, lane, wave, acc, mbuf);
  __syncthreads();
}

// layer0 (K=32) via MFMA; A-fragments (av) built in registers by the caller.
template <int NRT>
__device__ __forceinline__ void layer0_mfma(char* lds, const bf16x8* av, const bf16x8 b0f[4],
                                            const float* bias, int lane, int wave) {
  f32x4 acc[NRT][4];
  acc_init<NRT, true>(acc, bias, lane, wave);
  __builtin_amdgcn_s_setprio(1);
#pragma unroll
  for (int rt = 0; rt < NRT; ++rt) {
#pragma unroll
    for (int i = 0; i < 4; ++i)
      acc[rt][i] = __builtin_amdgcn_mfma_f32_16x16x32_bf16(b0f[i], av[rt], acc[rt][i], 0, 0, 0);
  }
  __builtin_amdgcn_s_setprio(0);
  epilogue<NRT, true, true, false>(lds, lane, wave, acc, nullptr);
  __syncthreads();
}

// ------------------ weight convert/transpose/pack to bf16 (tanh layers pre-scaled) ------------------
struct ConvArgs { const float* src[14]; };
__global__ void K_conv(ConvArgs a, __bf16* wt, unsigned* gkeys) {
  int job = blockIdx.x, t = threadIdx.x, y = blockIdx.y;
  if (job == 14) {
    if (y == 0) { gkeys[t] = 0u; gkeys[256 + t] = 0u; }
    return;
  }
  if (job >= 11) {  // W0 minis
    if (y >= 2) return;
    const float* s = a.src[job];
    __bf16* d = wt + (size_t)11 * WT_SLOT + (job - 11) * 8192;
#pragma unroll
    for (int it = 0; it < 16; ++it) {
      int p = y * 4096 + it * 256 + t;
      int nt = (p >> 9) & 15, ln = (p >> 3) & 63, j = p & 7;
      int n = nt * 16 + (ln & 15);
      int k = ((ln >> 4) << 3) + j;
      d[p] = (k < 3) ? (__bf16)(TANH_K * s[k * 256 + n]) : (__bf16)0.f;
    }
    return;
  }
  const float scale = (job >= 9 || (job % 3) != 2) ? TANH_K : 1.0f;
  const float* s = a.src[job];
  __bf16* d = wt + (size_t)job * WT_SLOT;
#pragma unroll
  for (int it = 0; it < 16; ++it) {
    int p = y * 4096 + it * 256 + t;
    int ks = p >> 13, nt = (p >> 9) & 15, ln = (p >> 3) & 63, j = p & 7;
    int n = nt * 16 + (ln & 15);
    int k = ks * 32 + ((ln >> 4) << 3) + j;
    d[p] = (__bf16)(scale * s[(k << 8) | n]);
  }
}

// ------------------ big fused MLP (tb & br) + column max: 64-row tiles, de-phased ------------------
struct BigArgs {
  const float* x;
  const __bf16* wt;
  const float* b0[2]; const float* b1[2]; const float* b2[2]; const float* b3[2];
  unsigned* gkeys;
};
__global__ __launch_bounds__(256, 3) void K_big(BigArgs a) {
  __shared__ char lds[32768];
  __shared__ float mbuf[256];
  // De-phase co-resident blocks by ~1/3 layer each so MFMA and epilogue-VALU phases
  // of different blocks overlap on the shared SIMD pipes (s_sleep(24) ~= 1536 clks).
  {
    int ph = blockIdx.x % 3;
    if (ph == 1) __builtin_amdgcn_s_sleep(24);
    else if (ph == 2) { __builtin_amdgcn_s_sleep(24); __builtin_amdgcn_s_sleep(24); }
  }
  int tid = threadIdx.x, lane = tid & 63, wave = tid >> 6;
  int mlp = blockIdx.y;
  int row0 = blockIdx.x << 6;          // 64 rows per block; 64 | NPTS exactly
  const __bf16* wt = a.wt + (size_t)(mlp * 3) * WT_SLOT;
  const __bf16* w0f = a.wt + (size_t)11 * WT_SLOT + mlp * 8192;
  const int rlo = lane & 15;
  bf16x8 av[4];
  {
    const float* xr = a.x + (size_t)row0 * 3;
#pragma unroll
    for (int rt = 0; rt < 4; ++rt) {
      bf16x8 v;
#pragma unroll
      for (int j = 0; j < 8; ++j) v[j] = (__bf16)0.f;
      if (lane < 16) {
        const float* p = xr + (rt * 16 + rlo) * 3;
        v[0] = (__bf16)p[0]; v[1] = (__bf16)p[1]; v[2] = (__bf16)p[2];
      }
      av[rt] = v;
    }
  }
  bf16x8 b0f[4];
#pragma unroll
  for (int i = 0; i < 4; ++i) b0f[i] = *(const bf16x8*)(w0f + (wave * 4 + i) * 512 + lane * 8);
  bf16x8 br0[4], br1[4];
  load_bquad(wt, wave, lane, 0, br0);
  layer0_mfma<4>(lds, av, b0f, a.b0[mlp], lane, wave);
  layer256_quad<4, true, true, false>(lds, wt, wt + WT_SLOT, a.b1[mlp], lane, wave, nullptr, br0, br1);
  layer256_quad<4, true, true, false>(lds, wt + WT_SLOT, wt + 2 * WT_SLOT, a.b2[mlp], lane, wave, nullptr, br0, br1);
  layer256_quad<4, false, false, true>(lds, wt + 2 * WT_SLOT, wt + 2 * WT_SLOT, a.b3[mlp], lane, wave, mbuf, br0, br1);
  atomicMax(a.gkeys + mlp * 256 + tid, fkey(mbuf[tid]));
}

// ------------------ patch membership / ordered compaction ------------------
__device__ __forceinline__ bool in_patch(const float* x, int r) {
  float a = x[r * 3], b = x[r * 3 + 1], c = x[r * 3 + 2];
  int c0 = min(max((int)floorf(a * 10.0f), 0), 9);
  int c1 = min(max((int)floorf(b * 10.0f), 0), 9);
  int c2 = min(max((int)floorf(c * 10.0f), 0), 9);
  return (c0 == 9) && (c1 == 9) && (c2 == 5);  // patch id 995
}
__global__ void K_count(const float* x, unsigned* counts) {
  __shared__ unsigned sw[4];
  int b = blockIdx.x, t = threadIdx.x;
  int base = b * 1024 + t * 4;
  unsigned c = 0;
#pragma unroll
  for (int j = 0; j < 4; ++j) c += in_patch(x, base + j) ? 1u : 0u;
#pragma unroll
  for (int o = 1; o < 64; o <<= 1) c += __shfl_xor((int)c, o, 64);
  if ((t & 63) == 0) sw[t >> 6] = c;
  __syncthreads();
  if (t == 0) counts[b] = sw[0] + sw[1] + sw[2] + sw[3];
}
__global__ void K_scan(const unsigned* counts, unsigned* bases) {
  __shared__ unsigned s[256];
  int t = threadIdx.x;
  unsigned c = counts[t];
  s[t] = c; __syncthreads();
  for (int o = 1; o < 256; o <<= 1) {
    unsigned v = (t >= o) ? s[t - o] : 0u;
    __syncthreads();
    s[t] += v;
    __syncthreads();
  }
  bases[t] = s[t] - c;
}
__global__ void K_fill(const float* x, const unsigned* bases, int* idx) {
  __shared__ unsigned s[256];
  int b = blockIdx.x, t = threadIdx.x;
  int base = b * 1024 + t * 4;
  unsigned fm = 0, c = 0;
#pragma unroll
  for (int j = 0; j < 4; ++j) {
    bool f = in_patch(x, base + j);
    fm |= (f ? 1u : 0u) << j;
    c += f ? 1u : 0u;
  }
  s[t] = c; __syncthreads();
  for (int o = 1; o < 256; o <<= 1) {
    unsigned v = (t >= o) ? s[t - o] : 0u;
    __syncthreads();
    s[t] += v;
    __syncthreads();
  }
  unsigned pos = bases[b] + s[t] - c;
#pragma unroll
  for (int j = 0; j < 4; ++j)
    if (fm & (1u << j)) idx[pos++] = base + j;
}

// ------------------ finalize params + broadcast part of o-layer1 (unscaled) ------------------
__global__ void K_vec(const unsigned* gkeys, const float* ow0, const float* ob0, float* vec0) {
  __shared__ float gp[256], lp[256];
  int t = threadIdx.x;
  gp[t] = unfkey(gkeys[t]);        // tb -> global_param
  lp[t] = unfkey(gkeys[256 + t]);  // br -> local_param
  __syncthreads();
  float acc = ob0[t];
  for (int k = 0; k < 256; ++k) {
    acc = fmaf(lp[k], ow0[(256 + k) * 256 + t], acc);
    acc = fmaf(gp[k], ow0[(512 + k) * 256 + t], acc);
  }
  vec0[t] = acc;
}

// ------------------ patch pipeline: tr-MLP + out-MLP + gt copy (r12-verified pair path) ------------------
struct SmallArgs {
  const float* x; const float* y; const int* idx; int MM;
  const __bf16* wt;
  const float* trb0; const float* trb1; const float* trb2; const float* trb3;
  const float* vec0; const float* ob1; const float* ow2; const float* ob2;
  float* out;
};
__global__ __launch_bounds__(256, 2) void K_small(SmallArgs a) {
  __shared__ char lds[65536];
  int tid = threadIdx.x, lane = tid & 63, wave = tid >> 6;
  int pr0 = blockIdx.x << 7;
  const __bf16* wt6 = a.wt + (size_t)6 * WT_SLOT;
  const __bf16* w0f = a.wt + (size_t)11 * WT_SLOT + 2 * 8192;  // tr mini
  const int rlo = lane & 15;
  bf16x8 av[8];
  {
#pragma unroll
    for (int rt = 0; rt < 8; ++rt) {
      bf16x8 v;
#pragma unroll
      for (int j = 0; j < 8; ++j) v[j] = (__bf16)0.f;
      if (lane < 16) {
        int j = a.idx[min(pr0 + rt * 16 + rlo, a.MM - 1)];
        v[0] = (__bf16)a.x[j * 3]; v[1] = (__bf16)a.x[j * 3 + 1]; v[2] = (__bf16)a.x[j * 3 + 2];
      }
      av[rt] = v;
    }
  }
  if (tid < 128 && pr0 + tid < a.MM) a.out[a.MM + pr0 + tid] = a.y[a.idx[pr0 + tid]];
  bf16x8 b0f[4];
#pragma unroll
  for (int i = 0; i < 4; ++i) b0f[i] = *(const bf16x8*)(w0f + (wave * 4 + i) * 512 + lane * 8);
  bf16x8 br0[8], br1[8];
  load_bpair(wt6, wave, lane, 0, br0);
  layer0_mfma<8>(lds, av, b0f, a.trb0, lane, wave);
  layer256_pair<8, true, true, false>(lds, wt6, wt6 + WT_SLOT, a.trb1, lane, wave, nullptr, br0, br1);
  layer256_pair<8, true, true, false>(lds, wt6 + WT_SLOT, wt6 + 2 * WT_SLOT, a.trb2, lane, wave, nullptr, br0, br1);
  layer256_pair<8, false, true, false>(lds, wt6 + 2 * WT_SLOT, a.wt + (size_t)9 * WT_SLOT, a.trb3, lane, wave, nullptr, br0, br1);  // local_coord
  layer256_pair<8, true, true, false>(lds, a.wt + (size_t)9 * WT_SLOT, a.wt + (size_t)10 * WT_SLOT, a.vec0, lane, wave, nullptr, br0, br1);  // o1
  layer256_pair<8, true, true, false>(lds, a.wt + (size_t)10 * WT_SLOT, a.wt + (size_t)10 * WT_SLOT, a.ob1, lane, wave, nullptr, br0, br1);  // o2
  {  // o3: 256 -> 1 dot per row, fp32 out
    int r = tid >> 1, half = tid & 1, pr = pr0 + r;
    float s = 0.f;
    for (int i = 0; i < 128; ++i) {
      int c = (half << 7) + i;
      s = fmaf((float)*(const __bf16*)(lds + lds_off(r, 2 * c)), a.ow2[c], s);
    }
    s += __shfl_xor(s, 1, 64);
    if (half == 0 && pr < a.MM) a.out[pr] = s + a.ob2[0];
  }
}

extern "C" void kernel_launch(void* const* d_in, const int* in_sizes, int n_in,
                              void* d_out, int out_size, void* d_ws, size_t ws_size,
                              hipStream_t stream) {
  const float* x = (const float*)d_in[0];
  const float* y = (const float*)d_in[1];
  char* ws = (char*)d_ws;
  unsigned* gkeys = (unsigned*)(ws + WS_GKEYS);
  float* vec0 = (float*)(ws + WS_VEC0);
  unsigned* counts = (unsigned*)(ws + WS_COUNTS);
  unsigned* bases = (unsigned*)(ws + WS_BASES);
  int* idx = (int*)(ws + WS_IDX);
  __bf16* wt = (__bf16*)(ws + WS_WT);
  int MM = out_size / 2;

  ConvArgs ca;
  for (int m = 0; m < 3; ++m)           // 0=tb,1=br,2=tr ; L -> w_{L+1}
    for (int L = 0; L < 3; ++L)
      ca.src[m * 3 + L] = (const float*)d_in[2 + m * 8 + 2 * (L + 1)];
  ca.src[9] = (const float*)d_in[26];   // o_w0 (top 256 rows used)
  ca.src[10] = (const float*)d_in[28];  // o_w1
  ca.src[11] = (const float*)d_in[2];   // tb_w0 (3x256)
  ca.src[12] = (const float*)d_in[10];  // br_w0
  ca.src[13] = (const float*)d_in[18];  // tr_w0
  hipLaunchKernelGGL(K_conv, dim3(15, 16), dim3(256), 0, stream, ca, wt, gkeys);

  K_count<<<256, 256, 0, stream>>>(x, counts);
  K_scan<<<1, 256, 0, stream>>>(counts, bases);
  K_fill<<<256, 256, 0, stream>>>(x, bases, idx);

  BigArgs ba;
  ba.x = x; ba.wt = wt; ba.gkeys = gkeys;
  ba.b0[0] = (const float*)d_in[3];  ba.b1[0] = (const float*)d_in[5];
  ba.b2[0] = (const float*)d_in[7];  ba.b3[0] = (const float*)d_in[9];
  ba.b0[1] = (const float*)d_in[11]; ba.b1[1] = (const float*)d_in[13];
  ba.b2[1] = (const float*)d_in[15]; ba.b3[1] = (const float*)d_in[17];
  K_big<<<dim3(NPTS / 64, 2), 256, 0, stream>>>(ba);

  K_vec<<<1, 256, 0, stream>>>(gkeys, (const float*)d_in[26], (const float*)d_in[27], vec0);

  if (MM > 0) {
    SmallArgs sa;
    sa.x = x; sa.y = y; sa.idx = idx; sa.MM = MM; sa.wt = wt;
    sa.trb0 = (const float*)d_in[19]; sa.trb1 = (const float*)d_in[21];
    sa.trb2 = (const float*)d_in[23]; sa.trb3 = (const float*)d_in[25];
    sa.vec0 = vec0;
    sa.ob1 = (const float*)d_in[29];
    sa.ow2 = (const float*)d_in[30]; sa.ob2 = (const float*)d_in[31];
    sa.out = (float*)d_out;
    K_small<<<(MM + 127) / 128, 256, 0, stream>>>(sa);
  }
}

// Round 16
// 251.638 us; speedup vs baseline: 1.3211x; 1.0816x over previous
//
#include <hip/hip_runtime.h>

typedef __bf16 bf16x8 __attribute__((ext_vector_type(8)));
typedef float f32x4 __attribute__((ext_vector_type(4)));

#define WT_SLOT 65536              // elements per 256x256 bf16 weight slot (packed fragment order)
#define WS_GKEYS 0                 // 512 u32 (tb keys, br keys)
#define WS_VEC0  4096              // 256 f32
#define WS_COUNTS 8192             // 256 u32
#define WS_BASES 12288             // 256 u32
#define WS_IDX   16384             // 4096 i32
#define WS_WT    32768             // 12 slots * 131072 B (slot 11 = 3 packed-W0 minis)

#define TANH_K 2.8853900817779268f   // 2*log2(e); tanh layers have W,b pre-scaled by this

__device__ __forceinline__ unsigned fkey(float f) {
  unsigned u = __float_as_uint(f);
  return (u & 0x80000000u) ? ~u : (u | 0x80000000u);
}
__device__ __forceinline__ float unfkey(unsigned k) {
  unsigned u = (k & 0x80000000u) ? (k & 0x7FFFFFFFu) : ~k;
  return __uint_as_float(u);
}
// swizzled LDS byte offset for a [128][256] bf16 tile, row stride 512B.
// (r&15) spread: the 16 rows co-read by a 16-lane quarter hit 16 distinct 16B slots.
__device__ __forceinline__ int lds_off(int r, int cb) {
  return r * 512 + (cb ^ ((r & 15) << 4));
}
// tanh from pre-scaled input t = 2log2e*x : 1 - 2/(exp2(t)+1)
__device__ __forceinline__ float tanh_scaled(float t) {
  float e = __builtin_amdgcn_exp2f(t);
  return fmaf(__builtin_amdgcn_rcpf(e + 1.0f), -2.0f, 1.0f);
}
// T12-verified packed bf16 convert (2 f32 -> 1 u32)
__device__ __forceinline__ unsigned cvt_pk_bf16(float lo, float hi) {
  unsigned d;
  asm("v_cvt_pk_bf16_f32 %0, %1, %2" : "=v"(d) : "v"(lo), "v"(hi));
  return d;
}

// Packed B layout: element (n = nt*16 + (l&15), k = ks*32 + (l>>4)*8 + j) at
// linear ks*8192 + nt*512 + l*8 + j. Wave w (of 4) owns nt = 4w..4w+3 (cols 64w..64w+63).
__device__ __forceinline__ void load_bpair(const __bf16* wt, int wave, int lane, int p,
                                           bf16x8 b[8]) {
  const __bf16* base = wt + p * 16384 + wave * 2048 + lane * 8;
#pragma unroll
  for (int h = 0; h < 2; ++h)
#pragma unroll
    for (int i = 0; i < 4; ++i)
      b[h * 4 + i] = *(const bf16x8*)(base + h * 8192 + i * 512);
}

// Swapped-operand MFMA: mfma(W_frag, A_frag, acc) -> lane holds rows rt*16+(lane&15),
// cols cbase + (lane>>4)*4 + rg (4 consecutive). setprio(1) favors this wave's MFMA
// burst against the co-resident block's epilogue waves (2 independent blocks/CU).
__device__ __forceinline__ void compute_pair(char* lds, const bf16x8 bc[8], int ksbase,
                                             int rlo, int khi2, f32x4 acc[8][4]) {
  __builtin_amdgcn_s_setprio(1);
#pragma unroll
  for (int h = 0; h < 2; ++h) {
    int cb = (ksbase + h) * 64 + khi2;   // byte column of this k-chunk
#pragma unroll
    for (int rt = 0; rt < 8; ++rt) {
      bf16x8 av = *(const bf16x8*)(lds + lds_off(rt * 16 + rlo, cb));
#pragma unroll
      for (int i = 0; i < 4; ++i)
        acc[rt][i] = __builtin_amdgcn_mfma_f32_16x16x32_bf16(bc[h * 4 + i], av, acc[rt][i], 0, 0, 0);
    }
  }
  __builtin_amdgcn_s_setprio(0);
}

// bias is already inside acc (C-operand init); epilogue = activation + pack + store.
template <bool TANH, bool WRITE, bool CMAX>
__device__ __forceinline__ void epilogue(char* lds, int lane, int wave,
                                         f32x4 acc[8][4], float* mbuf) {
  const int rlo = lane & 15;
  const int q4 = (lane >> 4) << 2;
#pragma unroll
  for (int i = 0; i < 4; ++i) {
    const int cbase = (wave * 4 + i) * 16 + q4;       // 4 consecutive cols per lane
    f32x4 cm;
#pragma unroll
    for (int rt = 0; rt < 8; ++rt) {
      f32x4 v;
#pragma unroll
      for (int rg = 0; rg < 4; ++rg) {
        float t = acc[rt][i][rg];
        if (TANH) t = tanh_scaled(t);
        v[rg] = t;
      }
      if (WRITE) {
        uint2 pv;
        pv.x = cvt_pk_bf16(v[0], v[1]);
        pv.y = cvt_pk_bf16(v[2], v[3]);
        *(uint2*)(lds + lds_off(rt * 16 + rlo, 2 * cbase)) = pv;
      }
      if (CMAX) {
        if (rt == 0) cm = v;
        else {
#pragma unroll
          for (int rg = 0; rg < 4; ++rg) cm[rg] = fmaxf(cm[rg], v[rg]);
        }
      }
    }
    if (CMAX) {  // reduce over rows (lane&15 across lanes), cols distinct per (q,rg)
#pragma unroll
      for (int rg = 0; rg < 4; ++rg) {
#pragma unroll
        for (int off = 1; off <= 8; off <<= 1)
          cm[rg] = fmaxf(cm[rg], __shfl_xor(cm[rg], off, 64));
      }
      if (rlo == 0) *(f32x4*)(mbuf + cbase) = cm;
    }
  }
}

// acc init = bias (x TANH_K for tanh layers, whose W is pre-scaled likewise)
template <bool TANH>
__device__ __forceinline__ void acc_init(f32x4 acc[8][4], const float* bias, int lane, int wave) {
  const int q4 = (lane >> 4) << 2;
#pragma unroll
  for (int i = 0; i < 4; ++i) {
    f32x4 bv = *(const f32x4*)(bias + (wave * 4 + i) * 16 + q4);
    if (TANH) {
#pragma unroll
      for (int rg = 0; rg < 4; ++rg) bv[rg] *= TANH_K;
    }
#pragma unroll
    for (int rt = 0; rt < 8; ++rt) acc[rt][i] = bv;
  }
}

// One 256->256 layer. Precondition: b0 holds THIS layer's pair0. Post: b0 holds wt_next pair0.
// CMAX-only layers (WRITE=false) skip the pre-epilogue barrier (no act-tile stores occur).
template <bool TANH, bool WRITE, bool CMAX>
__device__ __forceinline__ void layer256(char* lds, const __bf16* wt, const __bf16* wt_next,
                                         const float* bias, int lane, int wave, float* mbuf,
                                         bf16x8 b0[8], bf16x8 b1[8]) {
  const int rlo = lane & 15;
  const int khi2 = (lane >> 4) << 4;   // byte offset of k-subrange
  f32x4 acc[8][4];
  acc_init<TANH>(acc, bias, lane, wave);

  load_bpair(wt, wave, lane, 1, b1);
  compute_pair(lds, b0, 0, rlo, khi2, acc);
  load_bpair(wt, wave, lane, 2, b0);
  compute_pair(lds, b1, 2, rlo, khi2, acc);
  load_bpair(wt, wave, lane, 3, b1);
  compute_pair(lds, b0, 4, rlo, khi2, acc);
  load_bpair(wt_next, wave, lane, 0, b0);   // prefetch next layer's pair0
  compute_pair(lds, b1, 6, rlo, khi2, acc);

  if (WRITE) __syncthreads();               // act-tile reads done before overwrite
  epilogue<TANH, WRITE, CMAX>(lds, lane, wave, acc, mbuf);
  __syncthreads();
}

// layer0 (K=32) via MFMA; A-fragments (av) built in registers by the caller:
// lane<16 holds {x0,x1,x2,0...} for row rt*16+(lane&15); lanes>=16 all-zero.
__device__ __forceinline__ void layer0_mfma(char* lds, const bf16x8 av[8], const bf16x8 b0f[4],
                                            const float* bias, int lane, int wave) {
  f32x4 acc[8][4];
  acc_init<true>(acc, bias, lane, wave);
  __builtin_amdgcn_s_setprio(1);
#pragma unroll
  for (int rt = 0; rt < 8; ++rt) {
#pragma unroll
    for (int i = 0; i < 4; ++i)
      acc[rt][i] = __builtin_amdgcn_mfma_f32_16x16x32_bf16(b0f[i], av[rt], acc[rt][i], 0, 0, 0);
  }
  __builtin_amdgcn_s_setprio(0);
  epilogue<true, true, false>(lds, lane, wave, acc, nullptr);
  __syncthreads();
}

// ------------------ weight convert/transpose/pack to bf16 (tanh layers pre-scaled) ------------------
struct ConvArgs { const float* src[14]; };
__global__ void K_conv(ConvArgs a, __bf16* wt, unsigned* gkeys) {
  int job = blockIdx.x, t = threadIdx.x, y = blockIdx.y;
  if (job == 14) {
    if (y == 0) { gkeys[t] = 0u; gkeys[256 + t] = 0u; }
    return;
  }
  if (job >= 11) {  // W0 minis: (3,256) fp32 -> one K=32 fragment chunk, zero-padded, tanh-scaled
    if (y >= 2) return;
    const float* s = a.src[job];
    __bf16* d = wt + (size_t)11 * WT_SLOT + (job - 11) * 8192;
#pragma unroll
    for (int it = 0; it < 16; ++it) {
      int p = y * 4096 + it * 256 + t;
      int nt = (p >> 9) & 15, ln = (p >> 3) & 63, j = p & 7;
      int n = nt * 16 + (ln & 15);
      int k = ((ln >> 4) << 3) + j;
      d[p] = (k < 3) ? (__bf16)(TANH_K * s[k * 256 + n]) : (__bf16)0.f;
    }
    return;
  }
  // jobs 0..10: tanh layers (all except job%3==2 within 0..8) scaled by TANH_K
  const float scale = (job >= 9 || (job % 3) != 2) ? TANH_K : 1.0f;
  const float* s = a.src[job];
  __bf16* d = wt + (size_t)job * WT_SLOT;
#pragma unroll
  for (int it = 0; it < 16; ++it) {
    int p = y * 4096 + it * 256 + t;                 // packed linear index
    int ks = p >> 13, nt = (p >> 9) & 15, ln = (p >> 3) & 63, j = p & 7;
    int n = nt * 16 + (ln & 15);
    int k = ks * 32 + ((ln >> 4) << 3) + j;
    d[p] = (__bf16)(scale * s[(k << 8) | n]);        // src is [K][N] fp32 (first 256 rows)
  }
}

// ------------------ big fused MLP (tb & br) + column max ------------------
struct BigArgs {
  const float* x;
  const __bf16* wt;
  const float* b0[2]; const float* b1[2]; const float* b2[2]; const float* b3[2];
  unsigned* gkeys;
};
__global__ __launch_bounds__(256, 2) void K_big(BigArgs a) {
  __shared__ char lds[65536];          // act tile only
  __shared__ float mbuf[256];
  int tid = threadIdx.x, lane = tid & 63, wave = tid >> 6;
  int mlp = blockIdx.x >> 11;
  int row0 = (blockIdx.x & 2047) << 7;
  const __bf16* wt = a.wt + (size_t)(mlp * 3) * WT_SLOT;
  const __bf16* w0f = a.wt + (size_t)11 * WT_SLOT + mlp * 8192;
  // layer0 A-fragments in registers (no LDS staging)
  const int rlo = lane & 15;
  bf16x8 av[8];
  {
    const float* xr = a.x + (size_t)row0 * 3;
#pragma unroll
    for (int rt = 0; rt < 8; ++rt) {
      bf16x8 v;
#pragma unroll
      for (int j = 0; j < 8; ++j) v[j] = (__bf16)0.f;
      if (lane < 16) {
        const float* p = xr + (rt * 16 + rlo) * 3;
        v[0] = (__bf16)p[0]; v[1] = (__bf16)p[1]; v[2] = (__bf16)p[2];
      }
      av[rt] = v;
    }
  }
  bf16x8 b0f[4];
#pragma unroll
  for (int i = 0; i < 4; ++i) b0f[i] = *(const bf16x8*)(w0f + (wave * 4 + i) * 512 + lane * 8);
  bf16x8 br0[8], br1[8];
  load_bpair(wt, wave, lane, 0, br0);   // prefetch layer-1 pair0
  layer0_mfma(lds, av, b0f, a.b0[mlp], lane, wave);
  layer256<true, true, false>(lds, wt, wt + WT_SLOT, a.b1[mlp], lane, wave, nullptr, br0, br1);
  layer256<true, true, false>(lds, wt + WT_SLOT, wt + 2 * WT_SLOT, a.b2[mlp], lane, wave, nullptr, br0, br1);
  layer256<false, false, true>(lds, wt + 2 * WT_SLOT, wt + 2 * WT_SLOT, a.b3[mlp], lane, wave, mbuf, br0, br1);
  // per-column block max -> one atomic per column (max = commutative -> deterministic)
  atomicMax(a.gkeys + mlp * 256 + tid, fkey(mbuf[tid]));
}

// ------------------ patch membership / ordered compaction ------------------
__device__ __forceinline__ bool in_patch(const float* x, int r) {
  float a = x[r * 3], b = x[r * 3 + 1], c = x[r * 3 + 2];
  int c0 = min(max((int)floorf(a * 10.0f), 0), 9);
  int c1 = min(max((int)floorf(b * 10.0f), 0), 9);
  int c2 = min(max((int)floorf(c * 10.0f), 0), 9);
  return (c0 == 9) && (c1 == 9) && (c2 == 5);  // patch id 995
}
__global__ void K_count(const float* x, unsigned* counts) {
  __shared__ unsigned sw[4];
  int b = blockIdx.x, t = threadIdx.x;
  int base = b * 1024 + t * 4;
  unsigned c = 0;
#pragma unroll
  for (int j = 0; j < 4; ++j) c += in_patch(x, base + j) ? 1u : 0u;
#pragma unroll
  for (int o = 1; o < 64; o <<= 1) c += __shfl_xor((int)c, o, 64);
  if ((t & 63) == 0) sw[t >> 6] = c;
  __syncthreads();
  if (t == 0) counts[b] = sw[0] + sw[1] + sw[2] + sw[3];
}
__global__ void K_scan(const unsigned* counts, unsigned* bases) {
  __shared__ unsigned s[256];
  int t = threadIdx.x;
  unsigned c = counts[t];
  s[t] = c; __syncthreads();
  for (int o = 1; o < 256; o <<= 1) {
    unsigned v = (t >= o) ? s[t - o] : 0u;
    __syncthreads();
    s[t] += v;
    __syncthreads();
  }
  bases[t] = s[t] - c;
}
__global__ void K_fill(const float* x, const unsigned* bases, int* idx) {
  __shared__ unsigned s[256];
  int b = blockIdx.x, t = threadIdx.x;
  int base = b * 1024 + t * 4;
  unsigned fm = 0, c = 0;
#pragma unroll
  for (int j = 0; j < 4; ++j) {
    bool f = in_patch(x, base + j);
    fm |= (f ? 1u : 0u) << j;
    c += f ? 1u : 0u;
  }
  s[t] = c; __syncthreads();
  for (int o = 1; o < 256; o <<= 1) {
    unsigned v = (t >= o) ? s[t - o] : 0u;
    __syncthreads();
    s[t] += v;
    __syncthreads();
  }
  unsigned pos = bases[b] + s[t] - c;
#pragma unroll
  for (int j = 0; j < 4; ++j)
    if (fm & (1u << j)) idx[pos++] = base + j;
}

// ------------------ finalize params + broadcast part of o-layer1 (unscaled) ------------------
__global__ void K_vec(const unsigned* gkeys, const float* ow0, const float* ob0, float* vec0) {
  __shared__ float gp[256], lp[256];
  int t = threadIdx.x;
  gp[t] = unfkey(gkeys[t]);        // tb -> global_param
  lp[t] = unfkey(gkeys[256 + t]);  // br -> local_param
  __syncthreads();
  float acc = ob0[t];
  for (int k = 0; k < 256; ++k) {
    acc = fmaf(lp[k], ow0[(256 + k) * 256 + t], acc);
    acc = fmaf(gp[k], ow0[(512 + k) * 256 + t], acc);
  }
  vec0[t] = acc;
}

// ------------------ patch pipeline: tr-MLP + out-MLP + gt copy ------------------
struct SmallArgs {
  const float* x; const float* y; const int* idx; int MM;
  const __bf16* wt;
  const float* trb0; const float* trb1; const float* trb2; const float* trb3;
  const float* vec0; const float* ob1; const float* ow2; const float* ob2;
  float* out;
};
__global__ __launch_bounds__(256, 2) void K_small(SmallArgs a) {
  __shared__ char lds[65536];
  int tid = threadIdx.x, lane = tid & 63, wave = tid >> 6;
  int pr0 = blockIdx.x << 7;
  const __bf16* wt6 = a.wt + (size_t)6 * WT_SLOT;
  const __bf16* w0f = a.wt + (size_t)11 * WT_SLOT + 2 * 8192;  // tr mini
  const int rlo = lane & 15;
  bf16x8 av[8];
  {  // gathered layer0 A-fragments in registers
#pragma unroll
    for (int rt = 0; rt < 8; ++rt) {
      bf16x8 v;
#pragma unroll
      for (int j = 0; j < 8; ++j) v[j] = (__bf16)0.f;
      if (lane < 16) {
        int j = a.idx[min(pr0 + rt * 16 + rlo, a.MM - 1)];
        v[0] = (__bf16)a.x[j * 3]; v[1] = (__bf16)a.x[j * 3 + 1]; v[2] = (__bf16)a.x[j * 3 + 2];
      }
      av[rt] = v;
    }
  }
  if (tid < 128 && pr0 + tid < a.MM) a.out[a.MM + pr0 + tid] = a.y[a.idx[pr0 + tid]];
  bf16x8 b0f[4];
#pragma unroll
  for (int i = 0; i < 4; ++i) b0f[i] = *(const bf16x8*)(w0f + (wave * 4 + i) * 512 + lane * 8);
  bf16x8 br0[8], br1[8];
  load_bpair(wt6, wave, lane, 0, br0);
  layer0_mfma(lds, av, b0f, a.trb0, lane, wave);
  layer256<true, true, false>(lds, wt6, wt6 + WT_SLOT, a.trb1, lane, wave, nullptr, br0, br1);
  layer256<true, true, false>(lds, wt6 + WT_SLOT, wt6 + 2 * WT_SLOT, a.trb2, lane, wave, nullptr, br0, br1);
  layer256<false, true, false>(lds, wt6 + 2 * WT_SLOT, a.wt + (size_t)9 * WT_SLOT, a.trb3, lane, wave, nullptr, br0, br1);  // local_coord
  layer256<true, true, false>(lds, a.wt + (size_t)9 * WT_SLOT, a.wt + (size_t)10 * WT_SLOT, a.vec0, lane, wave, nullptr, br0, br1);  // o1
  layer256<true, true, false>(lds, a.wt + (size_t)10 * WT_SLOT, a.wt + (size_t)10 * WT_SLOT, a.ob1, lane, wave, nullptr, br0, br1);  // o2
  {  // o3: 256 -> 1 dot per row, fp32 out
    int r = tid >> 1, half = tid & 1, pr = pr0 + r;
    float s = 0.f;
    for (int i = 0; i < 128; ++i) {
      int c = (half << 7) + i;
      s = fmaf((float)*(const __bf16*)(lds + lds_off(r, 2 * c)), a.ow2[c], s);
    }
    s += __shfl_xor(s, 1, 64);
    if (half == 0 && pr < a.MM) a.out[pr] = s + a.ob2[0];
  }
}

extern "C" void kernel_launch(void* const* d_in, const int* in_sizes, int n_in,
                              void* d_out, int out_size, void* d_ws, size_t ws_size,
                              hipStream_t stream) {
  const float* x = (const float*)d_in[0];
  const float* y = (const float*)d_in[1];
  char* ws = (char*)d_ws;
  unsigned* gkeys = (unsigned*)(ws + WS_GKEYS);
  float* vec0 = (float*)(ws + WS_VEC0);
  unsigned* counts = (unsigned*)(ws + WS_COUNTS);
  unsigned* bases = (unsigned*)(ws + WS_BASES);
  int* idx = (int*)(ws + WS_IDX);
  __bf16* wt = (__bf16*)(ws + WS_WT);
  int MM = out_size / 2;

  ConvArgs ca;
  for (int m = 0; m < 3; ++m)           // 0=tb,1=br,2=tr ; L -> w_{L+1}
    for (int L = 0; L < 3; ++L)
      ca.src[m * 3 + L] = (const float*)d_in[2 + m * 8 + 2 * (L + 1)];
  ca.src[9] = (const float*)d_in[26];   // o_w0 (top 256 rows used)
  ca.src[10] = (const float*)d_in[28];  // o_w1
  ca.src[11] = (const float*)d_in[2];   // tb_w0 (3x256)
  ca.src[12] = (const float*)d_in[10];  // br_w0
  ca.src[13] = (const float*)d_in[18];  // tr_w0
  hipLaunchKernelGGL(K_conv, dim3(15, 16), dim3(256), 0, stream, ca, wt, gkeys);

  K_count<<<256, 256, 0, stream>>>(x, counts);
  K_scan<<<1, 256, 0, stream>>>(counts, bases);
  K_fill<<<256, 256, 0, stream>>>(x, bases, idx);

  BigArgs ba;
  ba.x = x; ba.wt = wt; ba.gkeys = gkeys;
  ba.b0[0] = (const float*)d_in[3];  ba.b1[0] = (const float*)d_in[5];
  ba.b2[0] = (const float*)d_in[7];  ba.b3[0] = (const float*)d_in[9];
  ba.b0[1] = (const float*)d_in[11]; ba.b1[1] = (const float*)d_in[13];
  ba.b2[1] = (const float*)d_in[15]; ba.b3[1] = (const float*)d_in[17];
  K_big<<<4096, 256, 0, stream>>>(ba);

  K_vec<<<1, 256, 0, stream>>>(gkeys, (const float*)d_in[26], (const float*)d_in[27], vec0);

  if (MM > 0) {
    SmallArgs sa;
    sa.x = x; sa.y = y; sa.idx = idx; sa.MM = MM; sa.wt = wt;
    sa.trb0 = (const float*)d_in[19]; sa.trb1 = (const float*)d_in[21];
    sa.trb2 = (const float*)d_in[23]; sa.trb3 = (const float*)d_in[25];
    sa.vec0 = vec0;
    sa.ob1 = (const float*)d_in[29];
    sa.ow2 = (const float*)d_in[30]; sa.ob2 = (const float*)d_in[31];
    sa.out = (float*)d_out;
    K_small<<<(MM + 127) / 128, 256, 0, stream>>>(sa);
  }
}